// Round 7
// baseline (175.944 us; speedup 1.0000x reference)
//
#include <hip/hip_runtime.h>
#include <math.h>

#define NF 128
#define HD 8
#define NPG 2000          // nodes per graph
#define EPB 8000          // edges per sort chunk (4 chunks per graph)
#define LPB 8             // layer blocks per graph
#define LNPB 250          // nodes per layer block
#define FNPB 1024         // nodes per feat block (1 node/thread)
#define SLOPE 0.01f

__device__ __forceinline__ float lrelu(float v) {
    return v > 0.0f ? v : SLOPE * v;
}
// bf16 helpers: RNE pack, cheap unpack
__device__ __forceinline__ unsigned short f2bf(float f) {
    unsigned int u = __float_as_uint(f);
    return (unsigned short)((u + 0x7FFFu + ((u >> 16) & 1u)) >> 16);
}
__device__ __forceinline__ float bfl(unsigned int p) {
    return __uint_as_float(p << 16);
}
__device__ __forceinline__ float bfh(unsigned int p) {
    return __uint_as_float(p & 0xFFFF0000u);
}
// async global->LDS, 16B per lane; dest = wave-uniform base + lane*16
__device__ __forceinline__ void gload_lds16(const void* g, void* l) {
    __builtin_amdgcn_global_load_lds(
        (const __attribute__((address_space(1))) unsigned int*)g,
        (__attribute__((address_space(3))) unsigned int*)l, 16, 0, 0);
}

// ---------------------------------------------------------------------------
// K1: fused [sort 0..255] + [feat 256..380: barrier-free streaming GEMV].
// Feat: 1 node/thread; W1a (4 KB) in LDS read via uniform-addr b128
// broadcasts (free); x rows stream per-lane (batch of 4 float4 = one 64B
// line/lane -> full line use). No x staging, no hot-path barrier; 2 blocks/CU
// (launch_bounds(1024,8) -> <=64 VGPR) so all 381 blocks co-resident and
// sort overlaps feat. Accumulation bit-identical to prior kernel (two
// half-K ascending chains, summed at the end).
// ---------------------------------------------------------------------------
__global__ __launch_bounds__(1024, 8) void k_featsort(
    const float* __restrict__ x, const float* __restrict__ W1a,
    const int* __restrict__ ei, unsigned short* __restrict__ t1b,
    unsigned short* __restrict__ gcolb, int* __restrict__ rpc,
    int N, int E, int NC)
{
    __shared__ union {
        struct { float wl[NF * HD]; } f;                          // 4 KB
        struct { int cnt[NPG]; unsigned int pck[EPB]; int srt[EPB];
                 int wtot[16]; int wpre[16]; } s;                 // 72.1 KB
    } sm;

    const int tid = threadIdx.x;

    if ((int)blockIdx.x < NC) {
        // ---------------- sort chunk b ----------------
        const int b = blockIdx.x;
        const int g = b >> 2;
        const int lane = tid & 63;
        const int wv = tid >> 6;
        const int nodeBase = g * NPG;
        const int e0 = b * EPB;

        for (int i = tid; i < NPG; i += 1024) sm.s.cnt[i] = 0;
        __syncthreads();

        // single global pass: count + stage packed (dl,src) to LDS
        for (int e = e0 + tid; e < e0 + EPB; e += 1024) {
            int src = ei[e] - nodeBase;               // < 2048
            int dl = ei[E + e] - nodeBase;            // < 2048
            sm.s.pck[e - e0] = ((unsigned int)dl << 11) | (unsigned int)src;
            atomicAdd(&sm.s.cnt[dl], 1);              // native ds_add_u32
        }
        __syncthreads();

        // block-wide exclusive scan; thread t owns pair (2t, 2t+1)
        int c0 = 0, c1 = 0;
        if (tid < 1000) { c0 = sm.s.cnt[2 * tid]; c1 = sm.s.cnt[2 * tid + 1]; }
        int s = c0 + c1;
        int isc = s;
#pragma unroll
        for (int d = 1; d < 64; d <<= 1) {
            int o = __shfl_up(isc, d);
            if (lane >= d) isc += o;
        }
        if (lane == 63) sm.s.wtot[wv] = isc;
        __syncthreads();
        if (wv == 0) {
            int v = (lane < 16) ? sm.s.wtot[lane] : 0;
            int iv = v;
#pragma unroll
            for (int d = 1; d < 16; d <<= 1) {
                int o = __shfl_up(iv, d);
                if (lane >= d) iv += o;
            }
            if (lane < 16) sm.s.wpre[lane] = iv - v;
        }
        __syncthreads();
        int excl = isc - s + sm.s.wpre[wv];

        int* rpb = rpc + (size_t)b * (NPG + 1);
        if (tid < 1000) {
            sm.s.cnt[2 * tid]     = excl;
            sm.s.cnt[2 * tid + 1] = excl + c0;
            rpb[2 * tid]     = excl;
            rpb[2 * tid + 1] = excl + c0;
        }
        if (tid == 0) rpb[NPG] = EPB;
        __syncthreads();

        // scatter pass: all-LDS (pck read -> rtn atomic -> srt write)
        for (int i = tid; i < EPB; i += 1024) {
            unsigned int p = sm.s.pck[i];
            int dl = (int)(p >> 11);
            int src = (int)(p & 2047u);
            int pos = atomicAdd(&sm.s.cnt[dl], 1);    // ds_add_rtn_u32
            sm.s.srt[pos] = src;
        }
        __syncthreads();

        // coalesced dump as ushort (pack 2 per uint)
        unsigned int* dst = (unsigned int*)(gcolb + (size_t)b * EPB);
        for (int i = tid; i < EPB / 2; i += 1024) {
            unsigned int lo = (unsigned int)sm.s.srt[2 * i] & 0xFFFFu;
            unsigned int hi = (unsigned int)sm.s.srt[2 * i + 1] << 16;
            dst[i] = lo | hi;
        }
    } else {
        // ---------------- feat block: 1024 nodes, streaming GEMV ----------
        const size_t base = (size_t)(blockIdx.x - NC) * FNPB;
        const int node = (int)base + tid;

        // stage W1a verbatim (k-major rows of 8): wl[k*8+col]
        sm.f.wl[tid] = W1a[tid];
        __syncthreads();

        const float4* xr = (const float4*)(x + (size_t)node * NF);
        const float4* w4 = (const float4*)sm.f.wl;    // w4[2k], w4[2k+1]
        float accL[8] = {0, 0, 0, 0, 0, 0, 0, 0};
        float accH[8] = {0, 0, 0, 0, 0, 0, 0, 0};

#pragma unroll
        for (int kb = 0; kb < 8; ++kb) {
            float4 r[4];
#pragma unroll
            for (int j = 0; j < 4; ++j) r[j] = xr[kb * 4 + j];
            float* acc = (kb < 4) ? accL : accH;      // kb is compile-time
#pragma unroll
            for (int c4 = 0; c4 < 4; ++c4) {
#pragma unroll
                for (int e = 0; e < 4; ++e) {
                    const int k = kb * 16 + c4 * 4 + e;
                    const float xs = (e == 0) ? r[c4].x : (e == 1) ? r[c4].y
                                   : (e == 2) ? r[c4].z : r[c4].w;
                    float4 wA = w4[k * 2];
                    float4 wB = w4[k * 2 + 1];
                    acc[0] += xs * wA.x; acc[1] += xs * wA.y;
                    acc[2] += xs * wA.z; acc[3] += xs * wA.w;
                    acc[4] += xs * wB.x; acc[5] += xs * wB.y;
                    acc[6] += xs * wB.z; acc[7] += xs * wB.w;
                }
            }
        }

        uint4 pk;
        pk.x = (unsigned int)f2bf(accL[0] + accH[0]) |
               ((unsigned int)f2bf(accL[1] + accH[1]) << 16);
        pk.y = (unsigned int)f2bf(accL[2] + accH[2]) |
               ((unsigned int)f2bf(accL[3] + accH[3]) << 16);
        pk.z = (unsigned int)f2bf(accL[4] + accH[4]) |
               ((unsigned int)f2bf(accL[5] + accH[5]) << 16);
        pk.w = (unsigned int)f2bf(accL[6] + accH[6]) |
               ((unsigned int)f2bf(accL[7] + accH[7]) << 16);
        ((uint4*)t1b)[node] = pk;                     // coalesced 16B/thread
    }
}

// ---------------------------------------------------------------------------
// Batched gather: 8 independent clamped col loads, then 8 predicated LDS
// gathers; rare tail for degree > 8.
// ---------------------------------------------------------------------------
#define GATHER_CHUNK(P)                                                       \
    {                                                                         \
        int b0 = rs[P], cnt = re[P] - b0;                                     \
        int sl[8];                                                            \
        _Pragma("unroll")                                                     \
        for (int j = 0; j < 8; ++j) {                                         \
            int idx = (j < cnt) ? (b0 + j) : 0;                               \
            sl[j] = colp[P][idx];                                             \
        }                                                                     \
        _Pragma("unroll")                                                     \
        for (int j = 0; j < 8; ++j) {                                         \
            float w = (j < cnt) ? 1.0f : 0.0f;                                \
            uint4 v = tbl[sl[j]];                                             \
            a0 += w * bfl(v.x); a1 += w * bfh(v.x);                           \
            a2 += w * bfl(v.y); a3 += w * bfh(v.y);                           \
            a4 += w * bfl(v.z); a5 += w * bfh(v.z);                           \
            a6 += w * bfl(v.w); a7 += w * bfh(v.w);                           \
        }                                                                     \
        for (int e2 = b0 + 8; e2 < b0 + cnt; ++e2) {                          \
            uint4 v = tbl[colp[P][e2]];                                       \
            a0 += bfl(v.x); a1 += bfh(v.x);                                   \
            a2 += bfl(v.y); a3 += bfh(v.y);                                   \
            a4 += bfl(v.z); a5 += bfh(v.z);                                   \
            a6 += bfl(v.w); a7 += bfh(v.w);                                   \
        }                                                                     \
    }

// ---------------------------------------------------------------------------
// K2: layer 1. 8 blocks/graph x 512 thr. 2 threads/node: half h gathers
// chunks {2h,2h+1}, shfl_xor(1) merges, half-0 runs MLP1 + u pack.
// tbl staged via global_load_lds (linear copy, 2048 slots incl. pad).
// ---------------------------------------------------------------------------
__global__ __launch_bounds__(512) void k_l1(
    const unsigned short* __restrict__ t1b, const int* __restrict__ rpc,
    const unsigned short* __restrict__ gcolb, unsigned short* __restrict__ ub,
    const float* __restrict__ b1a, const float* __restrict__ W1b,
    const float* __restrict__ b1b, const float* __restrict__ W2a)
{
    __shared__ uint4 tbl[2048];       // 32.8 KB (48 pad slots)
    __shared__ float wts[144];        // b1a[8] W1b[64] b1b[8] W2a[64]

    const int b = blockIdx.x;
    const int g = b >> 3;
    const int q = b & 7;
    const int tid = threadIdx.x;
    const int lane = tid & 63;
    const int wv = tid >> 6;

    if (tid < 144) {
        float v;
        if (tid < 8)       v = b1a[tid];
        else if (tid < 72) v = W1b[tid - 8];
        else if (tid < 80) v = b1b[tid - 72];
        else               v = W2a[tid - 80];
        wts[tid] = v;
    }

    {
        const uint4* src4 = (const uint4*)(t1b + (size_t)g * NPG * HD);
        char* tb = (char*)tbl;
#pragma unroll
        for (int i = 0; i < 4; ++i) {
            int s = wv * 256 + i * 64 + lane;         // 0..2047
            gload_lds16(src4 + s, tb + s * 16);
        }
    }
    __syncthreads();

    if (tid < 2 * LNPB) {
        const int node = tid >> 1;            // 0..249
        const int half = tid & 1;
        const int nl = q * LNPB + node;
        int rs[2], re[2];
        const unsigned short* colp[2];
#pragma unroll
        for (int p = 0; p < 2; ++p) {
            int ch = half * 2 + p;
            const int* rpb = rpc + (size_t)((g << 2) + ch) * (NPG + 1);
            colp[p] = gcolb + (size_t)((g << 2) + ch) * EPB;
            rs[p] = rpb[nl]; re[p] = rpb[nl + 1];
        }
        float a0 = 0, a1 = 0, a2 = 0, a3 = 0, a4 = 0, a5 = 0, a6 = 0, a7 = 0;
        GATHER_CHUNK(0) GATHER_CHUNK(1)
        // merge halves (partner = tid^1, same node)
        a0 += __shfl_xor(a0, 1); a1 += __shfl_xor(a1, 1);
        a2 += __shfl_xor(a2, 1); a3 += __shfl_xor(a3, 1);
        a4 += __shfl_xor(a4, 1); a5 += __shfl_xor(a5, 1);
        a6 += __shfl_xor(a6, 1); a7 += __shfl_xor(a7, 1);

        if (half == 0) {
            uint4 sv = tbl[nl];                       // self feature
            float z[HD];
            z[0] = lrelu(bfl(sv.x) + a0 + wts[0]); z[1] = lrelu(bfh(sv.x) + a1 + wts[1]);
            z[2] = lrelu(bfl(sv.y) + a2 + wts[2]); z[3] = lrelu(bfh(sv.y) + a3 + wts[3]);
            z[4] = lrelu(bfl(sv.z) + a4 + wts[4]); z[5] = lrelu(bfh(sv.z) + a5 + wts[5]);
            z[6] = lrelu(bfl(sv.w) + a6 + wts[6]); z[7] = lrelu(bfh(sv.w) + a7 + wts[7]);

            float h[HD];
#pragma unroll
            for (int j = 0; j < HD; ++j) {
                float acc = wts[72 + j];
#pragma unroll
                for (int c = 0; c < HD; ++c) acc += z[c] * wts[8 + c * HD + j];
                h[j] = lrelu(acc);
            }
            float uu[HD];
#pragma unroll
            for (int j = 0; j < HD; ++j) {
                float acc = 0.0f;
#pragma unroll
                for (int c = 0; c < HD; ++c) acc += h[c] * wts[80 + c * HD + j];
                uu[j] = acc;
            }
            uint4 pk;
            pk.x = (unsigned int)f2bf(uu[0]) | ((unsigned int)f2bf(uu[1]) << 16);
            pk.y = (unsigned int)f2bf(uu[2]) | ((unsigned int)f2bf(uu[3]) << 16);
            pk.z = (unsigned int)f2bf(uu[4]) | ((unsigned int)f2bf(uu[5]) << 16);
            pk.w = (unsigned int)f2bf(uu[6]) | ((unsigned int)f2bf(uu[7]) << 16);
            ((uint4*)ub)[(size_t)g * NPG + nl] = pk;
        }
    }
}

// ---------------------------------------------------------------------------
// K3: layer 2, same 2-thr/node structure over ub; MLP2 + FC1 + FC2 partials;
// plain-store per-block partial. k_fin finalizes.
// ---------------------------------------------------------------------------
__global__ __launch_bounds__(512) void k_l2(
    const unsigned short* __restrict__ ub, const int* __restrict__ rpc,
    const unsigned short* __restrict__ gcolb,
    const float* __restrict__ b2a, const float* __restrict__ W2b,
    const float* __restrict__ b2b, const float* __restrict__ Wf1,
    const float* __restrict__ bf1, const float* __restrict__ Wf2,
    float* __restrict__ bparts)
{
    __shared__ uint4 tbl[2048];       // 32.8 KB (48 pad slots)
    __shared__ float wts[89];         // b2a[8] W2b[64] b2b[8] Wf1[8] bf1[1]
    __shared__ float red[16];

    const int b = blockIdx.x;
    const int g = b >> 3;
    const int q = b & 7;
    const int tid = threadIdx.x;
    const int lane = tid & 63;
    const int wv = tid >> 6;

    if (tid < 89) {
        float v;
        if (tid < 8)       v = b2a[tid];
        else if (tid < 72) v = W2b[tid - 8];
        else if (tid < 80) v = b2b[tid - 72];
        else if (tid < 88) v = Wf1[tid - 80];
        else               v = bf1[0];
        wts[tid] = v;
    }

    {
        const uint4* src4 = (const uint4*)(ub + (size_t)g * NPG * HD);
        char* tb = (char*)tbl;
#pragma unroll
        for (int i = 0; i < 4; ++i) {
            int s = wv * 256 + i * 64 + lane;         // 0..2047
            gload_lds16(src4 + s, tb + s * 16);
        }
    }
    __syncthreads();

    float acc0 = 0.0f, acc1 = 0.0f;
    if (tid < 2 * LNPB) {
        const int node = tid >> 1;
        const int half = tid & 1;
        const int nl = q * LNPB + node;
        int rs[2], re[2];
        const unsigned short* colp[2];
#pragma unroll
        for (int p = 0; p < 2; ++p) {
            int ch = half * 2 + p;
            const int* rpb = rpc + (size_t)((g << 2) + ch) * (NPG + 1);
            colp[p] = gcolb + (size_t)((g << 2) + ch) * EPB;
            rs[p] = rpb[nl]; re[p] = rpb[nl + 1];
        }
        float a0 = 0, a1 = 0, a2 = 0, a3 = 0, a4 = 0, a5 = 0, a6 = 0, a7 = 0;
        GATHER_CHUNK(0) GATHER_CHUNK(1)
        a0 += __shfl_xor(a0, 1); a1 += __shfl_xor(a1, 1);
        a2 += __shfl_xor(a2, 1); a3 += __shfl_xor(a3, 1);
        a4 += __shfl_xor(a4, 1); a5 += __shfl_xor(a5, 1);
        a6 += __shfl_xor(a6, 1); a7 += __shfl_xor(a7, 1);

        if (half == 0) {
            uint4 sv = tbl[nl];
            float z[HD];
            z[0] = lrelu(bfl(sv.x) + a0 + wts[0]); z[1] = lrelu(bfh(sv.x) + a1 + wts[1]);
            z[2] = lrelu(bfl(sv.y) + a2 + wts[2]); z[3] = lrelu(bfh(sv.y) + a3 + wts[3]);
            z[4] = lrelu(bfl(sv.z) + a4 + wts[4]); z[5] = lrelu(bfh(sv.z) + a5 + wts[5]);
            z[6] = lrelu(bfl(sv.w) + a6 + wts[6]); z[7] = lrelu(bfh(sv.w) + a7 + wts[7]);

            float svl = wts[88];
#pragma unroll
            for (int j = 0; j < HD; ++j) {
                float acc = wts[72 + j];
#pragma unroll
                for (int c = 0; c < HD; ++c) acc += z[c] * wts[8 + c * HD + j];
                svl += lrelu(acc) * wts[80 + j];
            }
            float pf = lrelu(svl);
            float2 wf = *(const float2*)(Wf2 + (size_t)nl * 2);
            acc0 = pf * wf.x;
            acc1 = pf * wf.y;
        }
    }

#pragma unroll
    for (int off = 32; off > 0; off >>= 1) {
        acc0 += __shfl_down(acc0, off);
        acc1 += __shfl_down(acc1, off);
    }
    if (lane == 0) { red[wv * 2] = acc0; red[wv * 2 + 1] = acc1; }
    __syncthreads();

    if (tid == 0) {
        float y0 = 0.f, y1 = 0.f;
#pragma unroll
        for (int w = 0; w < 8; ++w) { y0 += red[w * 2]; y1 += red[w * 2 + 1]; }
        *(float2*)(bparts + (size_t)b * 2) = make_float2(y0, y1);
    }
}

// ---------------------------------------------------------------------------
// K4: finalize — one thread per graph sums 8 block partials, log_softmax.
// ---------------------------------------------------------------------------
__global__ __launch_bounds__(64) void k_fin(const float* __restrict__ bparts,
                                            const float* __restrict__ bf2,
                                            float* __restrict__ out, int Bn) {
    int g = threadIdx.x;
    if (g >= Bn) return;
    float y0 = bf2[0], y1 = bf2[1];
#pragma unroll
    for (int b = 0; b < LPB; ++b) {
        float2 v = *(const float2*)(bparts + (size_t)(g * LPB + b) * 2);
        y0 += v.x; y1 += v.y;
    }
    float m = fmaxf(y0, y1);
    float lse = m + logf(expf(y0 - m) + expf(y1 - m));
    out[g * 2 + 0] = y0 - lse;
    out[g * 2 + 1] = y1 - lse;
}

// ---------------------------------------------------------------------------
extern "C" void kernel_launch(void* const* d_in, const int* in_sizes, int n_in,
                              void* d_out, int out_size, void* d_ws, size_t ws_size,
                              hipStream_t stream) {
    const float* x   = (const float*)d_in[0];
    const int*   ei  = (const int*)  d_in[1];
    const float* W1a = (const float*)d_in[3];
    const float* b1a = (const float*)d_in[4];
    const float* W1b = (const float*)d_in[5];
    const float* b1b = (const float*)d_in[6];
    const float* W2a = (const float*)d_in[7];
    const float* b2a = (const float*)d_in[8];
    const float* W2b = (const float*)d_in[9];
    const float* b2b = (const float*)d_in[10];
    const float* Wf1 = (const float*)d_in[11];
    const float* bf1 = (const float*)d_in[12];
    const float* Wf2 = (const float*)d_in[13];
    const float* bf2 = (const float*)d_in[14];

    int N   = in_sizes[0] / NF;        // 128000
    int E   = in_sizes[1] / 2;         // 2048000
    int Bn  = N / NPG;                 // 64 graphs
    int NC  = Bn * 4;                  // 256 chunks

    // workspace carve-up (16B-aligned sections)
    unsigned short* t1b   = (unsigned short*)d_ws;              // N*8 bf16  2.0 MB
    unsigned short* ubuf  = t1b + (size_t)N * HD;               // N*8 bf16  2.0 MB
    unsigned short* gcolb = ubuf + (size_t)N * HD;              // E ushort  4.1 MB
    int*            rpc   = (int*)(gcolb + (size_t)E);          // NC*(NPG+1) 2.0 MB
    float*          bparts= (float*)(rpc + (size_t)NC * (NPG + 1) + 16); // 512*2

    k_featsort<<<NC + N / FNPB, 1024, 0, stream>>>(x, W1a, ei, t1b, gcolb, rpc,
                                                   N, E, NC);
    k_l1 <<<Bn * LPB, 512, 0, stream>>>(t1b, rpc, gcolb, ubuf, b1a, W1b, b1b, W2a);
    k_l2 <<<Bn * LPB, 512, 0, stream>>>(ubuf, rpc, gcolb, b2a, W2b, b2b, Wf1,
                                        bf1, Wf2, bparts);
    k_fin<<<1, 64, 0, stream>>>(bparts, bf2, (float*)d_out, Bn);
}

// Round 8
// 149.772 us; speedup vs baseline: 1.1747x; 1.1747x over previous
//
#include <hip/hip_runtime.h>
#include <math.h>

#define NF 128
#define HD 8
#define NPG 2000          // nodes per graph
#define EPB 8000          // edges per sort chunk (4 chunks per graph)
#define LPB 8             // layer blocks per graph
#define LNPB 250          // nodes per layer block
#define FNPB 64           // nodes per feat block (512 thr)
#define SLOPE 0.01f

__device__ __forceinline__ float lrelu(float v) {
    return v > 0.0f ? v : SLOPE * v;
}
// bf16 helpers: RNE pack, cheap unpack
__device__ __forceinline__ unsigned short f2bf(float f) {
    unsigned int u = __float_as_uint(f);
    return (unsigned short)((u + 0x7FFFu + ((u >> 16) & 1u)) >> 16);
}
__device__ __forceinline__ float bfl(unsigned int p) {
    return __uint_as_float(p << 16);
}
__device__ __forceinline__ float bfh(unsigned int p) {
    return __uint_as_float(p & 0xFFFF0000u);
}
// async global->LDS, 16B per lane; dest = wave-uniform base + lane*16
__device__ __forceinline__ void gload_lds16(const void* g, void* l) {
    __builtin_amdgcn_global_load_lds(
        (const __attribute__((address_space(1))) unsigned int*)g,
        (__attribute__((address_space(3))) unsigned int*)l, 16, 0, 0);
}

// ---------------------------------------------------------------------------
// K1: fused [sort 0..255] + [feat 256..2255], 512-thr blocks, 36.1 KB LDS
// union -> 4 blocks/CU (vs 2 for the old 1024-thr/72KB version — wave-slot
// capped). Sort drops pck staging (pass 1 counts via dst-only read; pass 2
// re-reads ei from L2 and scatters into ushort srt). Feat = R6's proven
// 64-node tile body (gload_lds + XOR-swizzled source), bit-identical math.
// Sort and feat blocks co-reside per CU so the x stream overlaps sort.
// ---------------------------------------------------------------------------
__global__ __launch_bounds__(512, 8) void k_featsort(
    const float* __restrict__ x, const float* __restrict__ W1a,
    const int* __restrict__ ei, unsigned short* __restrict__ t1b,
    unsigned short* __restrict__ gcolb, int* __restrict__ rpc,
    int N, int E, int NC)
{
    __shared__ union {
        struct { float tile[FNPB * NF]; float wl[8 * 132]; } f;   // 36.1 KB
        struct { int cnt[NPG]; unsigned short srt[EPB];
                 int wtot[8]; int wpre[8]; } s;                   // 24.1 KB
    } sm;

    const int tid = threadIdx.x;
    const int lane = tid & 63;
    const int wv = tid >> 6;                  // 0..7

    if ((int)blockIdx.x < NC) {
        // ---------------- sort chunk b ----------------
        const int b = blockIdx.x;
        const int g = b >> 2;
        const int nodeBase = g * NPG;
        const int e0 = b * EPB;

        for (int i = tid; i < NPG; i += 512) sm.s.cnt[i] = 0;
        __syncthreads();

        // pass 1: count (dst-only read)
        for (int e = e0 + tid; e < e0 + EPB; e += 512) {
            int dl = ei[E + e] - nodeBase;            // < 2048
            atomicAdd(&sm.s.cnt[dl], 1);              // native ds_add_u32
        }
        __syncthreads();

        // block-wide exclusive scan; thread t owns quad (4t..4t+3), t<500
        int c0 = 0, c1 = 0, c2 = 0, c3 = 0;
        if (tid < 500) {
            c0 = sm.s.cnt[4 * tid];     c1 = sm.s.cnt[4 * tid + 1];
            c2 = sm.s.cnt[4 * tid + 2]; c3 = sm.s.cnt[4 * tid + 3];
        }
        int s = c0 + c1 + c2 + c3;
        int isc = s;
#pragma unroll
        for (int d = 1; d < 64; d <<= 1) {
            int o = __shfl_up(isc, d);
            if (lane >= d) isc += o;
        }
        if (lane == 63) sm.s.wtot[wv] = isc;
        __syncthreads();
        if (wv == 0) {
            int v = (lane < 8) ? sm.s.wtot[lane] : 0;
            int iv = v;
#pragma unroll
            for (int d = 1; d < 8; d <<= 1) {
                int o = __shfl_up(iv, d);
                if (lane >= d) iv += o;
            }
            if (lane < 8) sm.s.wpre[lane] = iv - v;
        }
        __syncthreads();
        int excl = isc - s + sm.s.wpre[wv];

        int* rpb = rpc + (size_t)b * (NPG + 1);
        if (tid < 500) {
            int o0 = excl, o1 = excl + c0, o2 = o1 + c1, o3 = o2 + c2;
            sm.s.cnt[4 * tid]     = o0; sm.s.cnt[4 * tid + 1] = o1;
            sm.s.cnt[4 * tid + 2] = o2; sm.s.cnt[4 * tid + 3] = o3;
            rpb[4 * tid]     = o0; rpb[4 * tid + 1] = o1;
            rpb[4 * tid + 2] = o2; rpb[4 * tid + 3] = o3;
        }
        if (tid == 0) rpb[NPG] = EPB;
        __syncthreads();

        // pass 2: re-read ei (L2-hit) and scatter into ushort srt
        for (int e = e0 + tid; e < e0 + EPB; e += 512) {
            int src = ei[e] - nodeBase;               // < 2048
            int dl = ei[E + e] - nodeBase;
            int pos = atomicAdd(&sm.s.cnt[dl], 1);    // ds_add_rtn_u32
            sm.s.srt[pos] = (unsigned short)src;
        }
        __syncthreads();

        // CSR dump: srt is already packed ushort pairs -> direct uint copy
        unsigned int* dst = (unsigned int*)(gcolb + (size_t)b * EPB);
        const unsigned int* ss = (const unsigned int*)sm.s.srt;
        for (int i = tid; i < EPB / 2; i += 512) dst[i] = ss[i];
    } else {
        // ---------------- feat block: 64 nodes ----------------
        const size_t base = (size_t)(blockIdx.x - NC) * FNPB;

        // stage W1a^T: wl[col*132 + k] = W1a[k*8 + col]   (2 entries/thread)
#pragma unroll
        for (int i = 0; i < 2; ++i) {
            int idx = tid + i * 512;              // 0..1023
            int wcol = idx >> 7;                  // 0..7
            int wk   = idx & 127;                 // 0..127
            sm.f.wl[wcol * 132 + wk] = W1a[wk * 8 + wcol];
        }

        // x tile: 2048 slots of 16B; slot s=(n,j) sources global chunk
        // (n, j^(n&7)) so reads use the same XOR (banks spread).
        const float* xg = x + base * NF;
        char* tb = (char*)sm.f.tile;
#pragma unroll
        for (int i = 0; i < 4; ++i) {
            int s = wv * 256 + i * 64 + lane;     // linear 16B slot 0..2047
            int n = s >> 5, j = s & 31;
            gload_lds16(xg + n * NF + ((j ^ (n & 7)) << 2), tb + s * 16);
        }
        __syncthreads();

        const int col   = tid & 7;        // output column
        const int khalf = (tid >> 3) & 1; // k in [khalf*64, khalf*64+64)
        const int np    = tid >> 4;       // node pair 0..31
        const int n0    = np * 2;
        const int ex0 = n0 & 7, ex1 = (n0 + 1) & 7;

        const float*  tf = sm.f.tile;
        const float4* w4 = (const float4*)sm.f.wl;    // col stride 33 float4
        float acc0 = 0.0f, acc1 = 0.0f;
#pragma unroll 4
        for (int i = 0; i < 16; ++i) {
            int k4 = khalf * 16 + i;
            float4 r0 = *(const float4*)(tf + n0 * NF + ((k4 ^ ex0) << 2));
            float4 r1 = *(const float4*)(tf + (n0 + 1) * NF + ((k4 ^ ex1) << 2));
            float4 w  = w4[col * 33 + k4];
            acc0 += r0.x * w.x + r0.y * w.y + r0.z * w.z + r0.w * w.w;
            acc1 += r1.x * w.x + r1.y * w.y + r1.z * w.z + r1.w * w.w;
        }
        // merge k-halves (partner lane differs in bit 3)
        acc0 += __shfl_xor(acc0, 8);
        acc1 += __shfl_xor(acc1, 8);
        if (khalf == 0) {
            t1b[(base + n0) * HD + col]     = f2bf(acc0);
            t1b[(base + n0 + 1) * HD + col] = f2bf(acc1);
        }
    }
}

// ---------------------------------------------------------------------------
// Batched gather: 8 independent clamped col loads, then 8 predicated LDS
// gathers; rare tail for degree > 8.
// ---------------------------------------------------------------------------
#define GATHER_CHUNK(P)                                                       \
    {                                                                         \
        int b0 = rs[P], cnt = re[P] - b0;                                     \
        int sl[8];                                                            \
        _Pragma("unroll")                                                     \
        for (int j = 0; j < 8; ++j) {                                         \
            int idx = (j < cnt) ? (b0 + j) : 0;                               \
            sl[j] = colp[P][idx];                                             \
        }                                                                     \
        _Pragma("unroll")                                                     \
        for (int j = 0; j < 8; ++j) {                                         \
            float w = (j < cnt) ? 1.0f : 0.0f;                                \
            uint4 v = tbl[sl[j]];                                             \
            a0 += w * bfl(v.x); a1 += w * bfh(v.x);                           \
            a2 += w * bfl(v.y); a3 += w * bfh(v.y);                           \
            a4 += w * bfl(v.z); a5 += w * bfh(v.z);                           \
            a6 += w * bfl(v.w); a7 += w * bfh(v.w);                           \
        }                                                                     \
        for (int e2 = b0 + 8; e2 < b0 + cnt; ++e2) {                          \
            uint4 v = tbl[colp[P][e2]];                                       \
            a0 += bfl(v.x); a1 += bfh(v.x);                                   \
            a2 += bfl(v.y); a3 += bfh(v.y);                                   \
            a4 += bfl(v.z); a5 += bfh(v.z);                                   \
            a6 += bfl(v.w); a7 += bfh(v.w);                                   \
        }                                                                     \
    }

// ---------------------------------------------------------------------------
// K2: layer 1. 8 blocks/graph x 512 thr. 2 threads/node: half h gathers
// chunks {2h,2h+1}, shfl_xor(1) merges, half-0 runs MLP1 + u pack.
// tbl staged via global_load_lds (linear copy, 2048 slots incl. pad).
// ---------------------------------------------------------------------------
__global__ __launch_bounds__(512) void k_l1(
    const unsigned short* __restrict__ t1b, const int* __restrict__ rpc,
    const unsigned short* __restrict__ gcolb, unsigned short* __restrict__ ub,
    const float* __restrict__ b1a, const float* __restrict__ W1b,
    const float* __restrict__ b1b, const float* __restrict__ W2a)
{
    __shared__ uint4 tbl[2048];       // 32.8 KB (48 pad slots)
    __shared__ float wts[144];        // b1a[8] W1b[64] b1b[8] W2a[64]

    const int b = blockIdx.x;
    const int g = b >> 3;
    const int q = b & 7;
    const int tid = threadIdx.x;
    const int lane = tid & 63;
    const int wv = tid >> 6;

    if (tid < 144) {
        float v;
        if (tid < 8)       v = b1a[tid];
        else if (tid < 72) v = W1b[tid - 8];
        else if (tid < 80) v = b1b[tid - 72];
        else               v = W2a[tid - 80];
        wts[tid] = v;
    }

    {
        const uint4* src4 = (const uint4*)(t1b + (size_t)g * NPG * HD);
        char* tb = (char*)tbl;
#pragma unroll
        for (int i = 0; i < 4; ++i) {
            int s = wv * 256 + i * 64 + lane;         // 0..2047
            gload_lds16(src4 + s, tb + s * 16);
        }
    }
    __syncthreads();

    if (tid < 2 * LNPB) {
        const int node = tid >> 1;            // 0..249
        const int half = tid & 1;
        const int nl = q * LNPB + node;
        int rs[2], re[2];
        const unsigned short* colp[2];
#pragma unroll
        for (int p = 0; p < 2; ++p) {
            int ch = half * 2 + p;
            const int* rpb = rpc + (size_t)((g << 2) + ch) * (NPG + 1);
            colp[p] = gcolb + (size_t)((g << 2) + ch) * EPB;
            rs[p] = rpb[nl]; re[p] = rpb[nl + 1];
        }
        float a0 = 0, a1 = 0, a2 = 0, a3 = 0, a4 = 0, a5 = 0, a6 = 0, a7 = 0;
        GATHER_CHUNK(0) GATHER_CHUNK(1)
        // merge halves (partner = tid^1, same node)
        a0 += __shfl_xor(a0, 1); a1 += __shfl_xor(a1, 1);
        a2 += __shfl_xor(a2, 1); a3 += __shfl_xor(a3, 1);
        a4 += __shfl_xor(a4, 1); a5 += __shfl_xor(a5, 1);
        a6 += __shfl_xor(a6, 1); a7 += __shfl_xor(a7, 1);

        if (half == 0) {
            uint4 sv = tbl[nl];                       // self feature
            float z[HD];
            z[0] = lrelu(bfl(sv.x) + a0 + wts[0]); z[1] = lrelu(bfh(sv.x) + a1 + wts[1]);
            z[2] = lrelu(bfl(sv.y) + a2 + wts[2]); z[3] = lrelu(bfh(sv.y) + a3 + wts[3]);
            z[4] = lrelu(bfl(sv.z) + a4 + wts[4]); z[5] = lrelu(bfh(sv.z) + a5 + wts[5]);
            z[6] = lrelu(bfl(sv.w) + a6 + wts[6]); z[7] = lrelu(bfh(sv.w) + a7 + wts[7]);

            float h[HD];
#pragma unroll
            for (int j = 0; j < HD; ++j) {
                float acc = wts[72 + j];
#pragma unroll
                for (int c = 0; c < HD; ++c) acc += z[c] * wts[8 + c * HD + j];
                h[j] = lrelu(acc);
            }
            float uu[HD];
#pragma unroll
            for (int j = 0; j < HD; ++j) {
                float acc = 0.0f;
#pragma unroll
                for (int c = 0; c < HD; ++c) acc += h[c] * wts[80 + c * HD + j];
                uu[j] = acc;
            }
            uint4 pk;
            pk.x = (unsigned int)f2bf(uu[0]) | ((unsigned int)f2bf(uu[1]) << 16);
            pk.y = (unsigned int)f2bf(uu[2]) | ((unsigned int)f2bf(uu[3]) << 16);
            pk.z = (unsigned int)f2bf(uu[4]) | ((unsigned int)f2bf(uu[5]) << 16);
            pk.w = (unsigned int)f2bf(uu[6]) | ((unsigned int)f2bf(uu[7]) << 16);
            ((uint4*)ub)[(size_t)g * NPG + nl] = pk;
        }
    }
}

// ---------------------------------------------------------------------------
// K3: layer 2, same 2-thr/node structure over ub; MLP2 + FC1 + FC2 partials;
// plain-store per-block partial. k_fin finalizes.
// ---------------------------------------------------------------------------
__global__ __launch_bounds__(512) void k_l2(
    const unsigned short* __restrict__ ub, const int* __restrict__ rpc,
    const unsigned short* __restrict__ gcolb,
    const float* __restrict__ b2a, const float* __restrict__ W2b,
    const float* __restrict__ b2b, const float* __restrict__ Wf1,
    const float* __restrict__ bf1, const float* __restrict__ Wf2,
    float* __restrict__ bparts)
{
    __shared__ uint4 tbl[2048];       // 32.8 KB (48 pad slots)
    __shared__ float wts[89];         // b2a[8] W2b[64] b2b[8] Wf1[8] bf1[1]
    __shared__ float red[16];

    const int b = blockIdx.x;
    const int g = b >> 3;
    const int q = b & 7;
    const int tid = threadIdx.x;
    const int lane = tid & 63;
    const int wv = tid >> 6;

    if (tid < 89) {
        float v;
        if (tid < 8)       v = b2a[tid];
        else if (tid < 72) v = W2b[tid - 8];
        else if (tid < 80) v = b2b[tid - 72];
        else if (tid < 88) v = Wf1[tid - 80];
        else               v = bf1[0];
        wts[tid] = v;
    }

    {
        const uint4* src4 = (const uint4*)(ub + (size_t)g * NPG * HD);
        char* tb = (char*)tbl;
#pragma unroll
        for (int i = 0; i < 4; ++i) {
            int s = wv * 256 + i * 64 + lane;         // 0..2047
            gload_lds16(src4 + s, tb + s * 16);
        }
    }
    __syncthreads();

    float acc0 = 0.0f, acc1 = 0.0f;
    if (tid < 2 * LNPB) {
        const int node = tid >> 1;
        const int half = tid & 1;
        const int nl = q * LNPB + node;
        int rs[2], re[2];
        const unsigned short* colp[2];
#pragma unroll
        for (int p = 0; p < 2; ++p) {
            int ch = half * 2 + p;
            const int* rpb = rpc + (size_t)((g << 2) + ch) * (NPG + 1);
            colp[p] = gcolb + (size_t)((g << 2) + ch) * EPB;
            rs[p] = rpb[nl]; re[p] = rpb[nl + 1];
        }
        float a0 = 0, a1 = 0, a2 = 0, a3 = 0, a4 = 0, a5 = 0, a6 = 0, a7 = 0;
        GATHER_CHUNK(0) GATHER_CHUNK(1)
        a0 += __shfl_xor(a0, 1); a1 += __shfl_xor(a1, 1);
        a2 += __shfl_xor(a2, 1); a3 += __shfl_xor(a3, 1);
        a4 += __shfl_xor(a4, 1); a5 += __shfl_xor(a5, 1);
        a6 += __shfl_xor(a6, 1); a7 += __shfl_xor(a7, 1);

        if (half == 0) {
            uint4 sv = tbl[nl];
            float z[HD];
            z[0] = lrelu(bfl(sv.x) + a0 + wts[0]); z[1] = lrelu(bfh(sv.x) + a1 + wts[1]);
            z[2] = lrelu(bfl(sv.y) + a2 + wts[2]); z[3] = lrelu(bfh(sv.y) + a3 + wts[3]);
            z[4] = lrelu(bfl(sv.z) + a4 + wts[4]); z[5] = lrelu(bfh(sv.z) + a5 + wts[5]);
            z[6] = lrelu(bfl(sv.w) + a6 + wts[6]); z[7] = lrelu(bfh(sv.w) + a7 + wts[7]);

            float svl = wts[88];
#pragma unroll
            for (int j = 0; j < HD; ++j) {
                float acc = wts[72 + j];
#pragma unroll
                for (int c = 0; c < HD; ++c) acc += z[c] * wts[8 + c * HD + j];
                svl += lrelu(acc) * wts[80 + j];
            }
            float pf = lrelu(svl);
            float2 wf = *(const float2*)(Wf2 + (size_t)nl * 2);
            acc0 = pf * wf.x;
            acc1 = pf * wf.y;
        }
    }

#pragma unroll
    for (int off = 32; off > 0; off >>= 1) {
        acc0 += __shfl_down(acc0, off);
        acc1 += __shfl_down(acc1, off);
    }
    if (lane == 0) { red[wv * 2] = acc0; red[wv * 2 + 1] = acc1; }
    __syncthreads();

    if (tid == 0) {
        float y0 = 0.f, y1 = 0.f;
#pragma unroll
        for (int w = 0; w < 8; ++w) { y0 += red[w * 2]; y1 += red[w * 2 + 1]; }
        *(float2*)(bparts + (size_t)b * 2) = make_float2(y0, y1);
    }
}

// ---------------------------------------------------------------------------
// K4: finalize — one thread per graph sums 8 block partials, log_softmax.
// ---------------------------------------------------------------------------
__global__ __launch_bounds__(64) void k_fin(const float* __restrict__ bparts,
                                            const float* __restrict__ bf2,
                                            float* __restrict__ out, int Bn) {
    int g = threadIdx.x;
    if (g >= Bn) return;
    float y0 = bf2[0], y1 = bf2[1];
#pragma unroll
    for (int b = 0; b < LPB; ++b) {
        float2 v = *(const float2*)(bparts + (size_t)(g * LPB + b) * 2);
        y0 += v.x; y1 += v.y;
    }
    float m = fmaxf(y0, y1);
    float lse = m + logf(expf(y0 - m) + expf(y1 - m));
    out[g * 2 + 0] = y0 - lse;
    out[g * 2 + 1] = y1 - lse;
}

// ---------------------------------------------------------------------------
extern "C" void kernel_launch(void* const* d_in, const int* in_sizes, int n_in,
                              void* d_out, int out_size, void* d_ws, size_t ws_size,
                              hipStream_t stream) {
    const float* x   = (const float*)d_in[0];
    const int*   ei  = (const int*)  d_in[1];
    const float* W1a = (const float*)d_in[3];
    const float* b1a = (const float*)d_in[4];
    const float* W1b = (const float*)d_in[5];
    const float* b1b = (const float*)d_in[6];
    const float* W2a = (const float*)d_in[7];
    const float* b2a = (const float*)d_in[8];
    const float* W2b = (const float*)d_in[9];
    const float* b2b = (const float*)d_in[10];
    const float* Wf1 = (const float*)d_in[11];
    const float* bf1 = (const float*)d_in[12];
    const float* Wf2 = (const float*)d_in[13];
    const float* bf2 = (const float*)d_in[14];

    int N   = in_sizes[0] / NF;        // 128000
    int E   = in_sizes[1] / 2;         // 2048000
    int Bn  = N / NPG;                 // 64 graphs
    int NC  = Bn * 4;                  // 256 chunks

    // workspace carve-up (16B-aligned sections)
    unsigned short* t1b   = (unsigned short*)d_ws;              // N*8 bf16  2.0 MB
    unsigned short* ubuf  = t1b + (size_t)N * HD;               // N*8 bf16  2.0 MB
    unsigned short* gcolb = ubuf + (size_t)N * HD;              // E ushort  4.1 MB
    int*            rpc   = (int*)(gcolb + (size_t)E);          // NC*(NPG+1) 2.0 MB
    float*          bparts= (float*)(rpc + (size_t)NC * (NPG + 1) + 16); // 512*2

    k_featsort<<<NC + N / FNPB, 512, 0, stream>>>(x, W1a, ei, t1b, gcolb, rpc,
                                                  N, E, NC);
    k_l1 <<<Bn * LPB, 512, 0, stream>>>(t1b, rpc, gcolb, ubuf, b1a, W1b, b1b, W2a);
    k_l2 <<<Bn * LPB, 512, 0, stream>>>(ubuf, rpc, gcolb, b2a, W2b, b2b, Wf1,
                                        bf1, Wf2, bparts);
    k_fin<<<1, 64, 0, stream>>>(bparts, bf2, (float*)d_out, Bn);
}